// Round 16
// baseline (31.174 us; speedup 1.0000x reference)
//
#include <hip/hip_runtime.h>
#include <float.h>

#define NS 50
#define NP 64              // padded to power of two for bitonic network
#define B_DIM 8192
#define D_DIM 64
#define BD (B_DIM * D_DIM)
#define BLOCK 256
#define GRIDW 512          // 2 blocks/CU; each thread: 2 pairs = 4 columns

typedef __fp16 f16x2 __attribute__((ext_vector_type(2)));

__device__ __forceinline__ float block_reduce(float e, int tid) {
    #pragma unroll
    for (int off = 32; off > 0; off >>= 1)
        e += __shfl_down(e, off, 64);
    __shared__ float wsum[BLOCK / 64];
    const int lane = tid & 63;
    const int wid  = tid >> 6;
    if (lane == 0) wsum[wid] = e;
    __syncthreads();
    float bs = 0.0f;
    if (tid == 0) {
        #pragma unroll
        for (int w = 0; w < BLOCK / 64; ++w) bs += wsum[w];
    }
    return bs;
}

// Pack one pair's samples (from f2[]) into p[], accumulate first term.
__device__ __forceinline__ void pack_pair(const float2* f2, f16x2* p,
                                          float mA, float sdA, float tA,
                                          float mB, float sdB, float tB,
                                          float& first) {
    float f0 = 0.0f, f1 = 0.0f;
    #pragma unroll
    for (int k = 0; k < NS; ++k) {
        float sa = fmaf(f2[k].x, sdA, mA);
        float sb = fmaf(f2[k].y, sdB, mB);
        float dA = fabsf(sa - tA);
        float dB = fabsf(sb - tB);
        if (k & 1) f1 += dA + dB;
        else       f0 += dA + dB;
        p[k] = __builtin_amdgcn_cvt_pkrtz(sa, sb);
    }
    const f16x2 pad = {(__fp16)65504.0f, (__fp16)65504.0f};
    #pragma unroll
    for (int k = NS; k < NP; ++k) p[k] = pad;
    first += f0 + f1;
}

// Packed-f16 bitonic network (verified R14): sorts both lanes of p[].
__device__ __forceinline__ void sort_packed(f16x2* p) {
    #pragma unroll
    for (int k = 2; k <= NP; k <<= 1) {
        #pragma unroll
        for (int j = k >> 1; j > 0; j >>= 1) {
            #pragma unroll
            for (int i = 0; i < NP; ++i) {
                const int l = i ^ j;
                if (l > i) {
                    const bool up = ((i & k) == 0);
                    f16x2 x = p[i], y = p[l];
                    f16x2 lo = __builtin_elementwise_min(x, y);
                    f16x2 hi = __builtin_elementwise_max(x, y);
                    p[i] = up ? lo : hi;
                    p[l] = up ? hi : lo;
                }
            }
        }
    }
}

// Coefficient sum over sorted p[] (both lanes), f32 accumulate.
__device__ __forceinline__ float coef_sum(const f16x2* p) {
    float p0 = 0.0f, p1 = 0.0f;
    #pragma unroll
    for (int k = 0; k < NS; ++k) {
        const float c = (float)(2 * k - (NS - 1));
        float s = (float)p[k][0] + (float)p[k][1];
        if (k & 1) p1 = fmaf(c, s, p1);
        else       p0 = fmaf(c, s, p0);
    }
    return p0 + p1;
}

// Staggered 2-deep pipeline: pair A loads -> pack A (regs freed) -> ISSUE
// pair B loads -> sort A while B streams -> pack/sort B.
__device__ __forceinline__ float energy_quad(
    const float* __restrict__ mean, const float* __restrict__ variance,
    const float* __restrict__ noise, const float* __restrict__ target,
    int colA, int colB) {

    // ---- All params upfront; materialize so compiler's waitcnt for them
    // precedes the counted asm blocks.
    const float2 mvA = *(const float2*)(mean + colA);
    const float2 vvA = *(const float2*)(variance + colA);
    const float2 tvA = *(const float2*)(target + colA);
    const float2 mvB = *(const float2*)(mean + colB);
    const float2 vvB = *(const float2*)(variance + colB);
    const float2 tvB = *(const float2*)(target + colB);
    float mA0 = mvA.x, mA1 = mvA.y, tA0 = tvA.x, tA1 = tvA.y;
    float mB0 = mvB.x, mB1 = mvB.y, tB0 = tvB.x, tB1 = tvB.y;
    float sdA0 = sqrtf(vvA.x + 1e-6f), sdA1 = sqrtf(vvA.y + 1e-6f);
    float sdB0 = sqrtf(vvB.x + 1e-6f), sdB1 = sqrtf(vvB.y + 1e-6f);
    asm volatile("" : "+v"(mA0), "+v"(mA1), "+v"(tA0), "+v"(tA1),
                      "+v"(sdA0), "+v"(sdA1));
    asm volatile("" : "+v"(mB0), "+v"(mB1), "+v"(tB0), "+v"(tB1),
                      "+v"(sdB0), "+v"(sdB1));

    float first = 0.0f;

    // ---- ① Issue pair-A's 50 dwordx2 loads.
    float2 fa[NS];
    const unsigned offA = (unsigned)colA * 4u;
    #pragma unroll
    for (int k = 0; k < NS; ++k) {
        const unsigned ok = offA + (unsigned)k * (unsigned)(BD * 4);
        asm volatile("global_load_dwordx2 %0, %1, %2"
                     : "=v"(fa[k]) : "v"(ok), "s"(noise));
    }
    // ---- ② Drain A; pack A (fa[] dies here).
    asm volatile("s_waitcnt vmcnt(0)" ::: "memory");
    __builtin_amdgcn_sched_barrier(0);
    f16x2 pA[NP];
    pack_pair(fa, pA, mA0, sdA0, tA0, mA1, sdA1, tA1, first);
    __builtin_amdgcn_sched_barrier(0);

    // ---- ③ Issue pair-B's 50 loads (time-shifted burst).
    float2 fb[NS];
    const unsigned offB = (unsigned)colB * 4u;
    #pragma unroll
    for (int k = 0; k < NS; ++k) {
        const unsigned ok = offB + (unsigned)k * (unsigned)(BD * 4);
        asm volatile("global_load_dwordx2 %0, %1, %2"
                     : "=v"(fb[k]) : "v"(ok), "s"(noise));
    }
    __builtin_amdgcn_sched_barrier(0);

    // ---- ④ Sort A + coef A while B streams.
    sort_packed(pA);
    float pair = coef_sum(pA);
    __builtin_amdgcn_sched_barrier(0);

    // ---- ⑤ Drain B; pack/sort/coef B (pB reuses pA's registers).
    asm volatile("s_waitcnt vmcnt(0)" ::: "memory");
    __builtin_amdgcn_sched_barrier(0);
    f16x2 pB[NP];
    pack_pair(fb, pB, mB0, sdB0, tB0, mB1, sdB1, tB1, first);
    sort_packed(pB);
    pair += coef_sum(pB);

    float e = first * (1.0f / NS) - pair * (1.0f / 2450.0f);
    return e * (1.0f / (float)BD);   // pre-scale for global mean
}

// Stage 1: XCD-swizzled (GRIDW % 8 == 0, bijective), plain partial store.
__global__ __launch_bounds__(BLOCK, 2) void energy_partial_kernel(
    const float* __restrict__ mean, const float* __restrict__ variance,
    const float* __restrict__ noise, const float* __restrict__ target,
    float* __restrict__ partial) {
    const int tid  = threadIdx.x;
    const int wg   = (blockIdx.x & 7) * (GRIDW / 8) + (blockIdx.x >> 3);
    const int base = wg * (BLOCK * 4);          // 1024 columns per block
    const int colA = base + tid * 2;
    const int colB = base + BLOCK * 2 + tid * 2;
    float e = energy_quad(mean, variance, noise, target, colA, colB);
    float bs = block_reduce(e, tid);
    if (tid == 0) partial[blockIdx.x] = bs;
}

// Stage 2: one block sums the partials, writes the scalar output.
__global__ __launch_bounds__(BLOCK) void reduce_partial_kernel(
    const float* __restrict__ partial, float* __restrict__ out) {
    float e = 0.0f;
    #pragma unroll
    for (int i = 0; i < GRIDW / BLOCK; ++i)
        e += partial[i * BLOCK + threadIdx.x];
    float bs = block_reduce(e, threadIdx.x);
    if (threadIdx.x == 0) out[0] = bs;   // overwrites poison
}

// Fallback (ws too small): single-kernel atomic path, same pipeline.
__global__ __launch_bounds__(BLOCK, 2) void energy_atomic_kernel(
    const float* __restrict__ mean, const float* __restrict__ variance,
    const float* __restrict__ noise, const float* __restrict__ target,
    float* __restrict__ out) {
    const int tid  = threadIdx.x;
    const int wg   = (blockIdx.x & 7) * (GRIDW / 8) + (blockIdx.x >> 3);
    const int base = wg * (BLOCK * 4);
    const int colA = base + tid * 2;
    const int colB = base + BLOCK * 2 + tid * 2;
    float e = energy_quad(mean, variance, noise, target, colA, colB);
    float bs = block_reduce(e, tid);
    if (tid == 0) atomicAdd(out, bs);
}

extern "C" void kernel_launch(void* const* d_in, const int* in_sizes, int n_in,
                              void* d_out, int out_size, void* d_ws, size_t ws_size,
                              hipStream_t stream) {
    const float* mean     = (const float*)d_in[0];
    const float* variance = (const float*)d_in[1];
    const float* noise    = (const float*)d_in[2];
    const float* target   = (const float*)d_in[3];
    float* out = (float*)d_out;

    if (ws_size >= (size_t)GRIDW * sizeof(float)) {
        float* partial = (float*)d_ws;
        energy_partial_kernel<<<GRIDW, BLOCK, 0, stream>>>(mean, variance, noise,
                                                           target, partial);
        reduce_partial_kernel<<<1, BLOCK, 0, stream>>>(partial, out);
    } else {
        (void)hipMemsetAsync(out, 0, sizeof(float), stream);
        energy_atomic_kernel<<<GRIDW, BLOCK, 0, stream>>>(mean, variance, noise,
                                                          target, out);
    }
}

// Round 17
// 28.814 us; speedup vs baseline: 1.0819x; 1.0819x over previous
//
#include <hip/hip_runtime.h>
#include <float.h>
#include <utility>

#define NS 50
#define NP 64              // padded to power of two for bitonic network
#define B_DIM 8192
#define D_DIM 64
#define BD (B_DIM * D_DIM)
#define BLOCK 256
#define EPT 2
#define GRIDN (BD / (BLOCK * EPT))   // 1024 blocks

typedef __fp16 f16x2 __attribute__((ext_vector_type(2)));

// s_waitcnt simm16 encoding (gfx9/CDNA): vmcnt[3:0]|[15:14], expcnt[6:4]=7
// (no wait), lgkmcnt[11:8]=15 (no wait).
__device__ __forceinline__ constexpr int vmcnt_enc(int n) {
    return (n & 15) | (7 << 4) | (15 << 8) | ((n >> 4) << 14);
}

__device__ __forceinline__ float block_reduce(float e, int tid) {
    #pragma unroll
    for (int off = 32; off > 0; off >>= 1)
        e += __shfl_down(e, off, 64);
    __shared__ float wsum[BLOCK / 64];
    const int lane = tid & 63;
    const int wid  = tid >> 6;
    if (lane == 0) wsum[wid] = e;
    __syncthreads();
    float bs = 0.0f;
    if (tid == 0) {
        #pragma unroll
        for (int w = 0; w < BLOCK / 64; ++w) bs += wsum[w];
    }
    return bs;
}

// Incremental drain: rows retire in issue order, so vmcnt(NS-1-K) == rows
// 0..K landed. Pack row K (fma+abs-diff+cvt) while rows K+1.. still stream.
template <int K>
__device__ __forceinline__ void pack_row(const float2* fa, f16x2* p,
                                         float mA, float sdA, float tA,
                                         float mB, float sdB, float tB,
                                         float& f0, float& f1) {
    __builtin_amdgcn_s_waitcnt(vmcnt_enc(NS - 1 - K));
    __builtin_amdgcn_sched_barrier(0);   // rule #18: no hoist above the wait
    float sa = fmaf(fa[K].x, sdA, mA);
    float sb = fmaf(fa[K].y, sdB, mB);
    float dA = fabsf(sa - tA);
    float dB = fabsf(sb - tB);
    if (K & 1) f1 += dA + dB;
    else       f0 += dA + dB;
    p[K] = __builtin_amdgcn_cvt_pkrtz(sa, sb);
}

template <size_t... I>
__device__ __forceinline__ void pack_all(std::index_sequence<I...>,
                                         const float2* fa, f16x2* p,
                                         float mA, float sdA, float tA,
                                         float mB, float sdB, float tB,
                                         float& f0, float& f1) {
    (pack_row<(int)I>(fa, p, mA, sdA, tA, mB, sdB, tB, f0, f1), ...);
}

// Two elements per thread, ONE packed-f16 bitonic network sorting both
// (verified R14/R15, absmax 0.0), now with incremental load-drain.
__device__ __forceinline__ float energy_pair_packed(
    const float* __restrict__ mean, const float* __restrict__ variance,
    const float* __restrict__ noise, const float* __restrict__ target,
    int col0) {

    // ---- Params first; materialize so the compiler's own vmcnt-drain for
    // them lands BEFORE the counted asm-load block (keeps vmcnt math exact).
    const float2 mv = *(const float2*)(mean + col0);
    const float2 vv = *(const float2*)(variance + col0);
    const float2 tv = *(const float2*)(target + col0);
    float mA = mv.x, mB = mv.y;
    float tA = tv.x, tB = tv.y;
    float sdA = sqrtf(vv.x + 1e-6f);
    float sdB = sqrtf(vv.y + 1e-6f);
    asm volatile("" : "+v"(mA), "+v"(tA), "+v"(sdA), "+v"(mB), "+v"(tB), "+v"(sdB));

    // ---- 50 dwordx2 loads (adjacent columns), order pinned, all in flight.
    float2 f2[NS];
    const unsigned voff = (unsigned)col0 * 4u;
    #pragma unroll
    for (int k = 0; k < NS; ++k) {
        const unsigned ok = voff + (unsigned)k * (unsigned)(BD * 4);
        asm volatile("global_load_dwordx2 %0, %1, %2"
                     : "=v"(f2[k]) : "v"(ok), "s"(noise));
    }
    __builtin_amdgcn_sched_barrier(0);

    // ---- Incremental drain + pack: row k consumed as it arrives.
    float fA0 = 0.0f, fA1 = 0.0f;
    f16x2 p[NP];
    pack_all(std::make_index_sequence<NS>{}, f2, p,
             mA, sdA, tA, mB, sdB, tB, fA0, fA1);
    const f16x2 pad = {(__fp16)65504.0f, (__fp16)65504.0f};
    #pragma unroll
    for (int k = NS; k < NP; ++k) p[k] = pad;

    // ---- Packed bitonic sort: one network sorts BOTH lanes via
    // v_pk_min_f16/v_pk_max_f16. Compile-time dirs -> pure min/max.
    #pragma unroll
    for (int k = 2; k <= NP; k <<= 1) {
        #pragma unroll
        for (int j = k >> 1; j > 0; j >>= 1) {
            #pragma unroll
            for (int i = 0; i < NP; ++i) {
                const int l = i ^ j;
                if (l > i) {
                    const bool up = ((i & k) == 0);
                    f16x2 x = p[i], y = p[l];
                    f16x2 lo = __builtin_elementwise_min(x, y);
                    f16x2 hi = __builtin_elementwise_max(x, y);
                    p[i] = up ? lo : hi;   // compile-time select
                    p[l] = up ? hi : lo;
                }
            }
        }
    }

    // ---- Pair term via sort identity, accumulated in f32.
    float pA0 = 0.0f, pA1 = 0.0f;
    #pragma unroll
    for (int k = 0; k < NS; ++k) {
        const float c = (float)(2 * k - (NS - 1));
        float s = (float)p[k][0] + (float)p[k][1];
        if (k & 1) pA1 = fmaf(c, s, pA1);
        else       pA0 = fmaf(c, s, pA0);
    }

    float e = (fA0 + fA1) * (1.0f / NS) - (pA0 + pA1) * (1.0f / 2450.0f);
    return e * (1.0f / (float)BD);   // pre-scale for global mean
}

// Stage 1: XCD-swizzled (GRIDN % 8 == 0, bijective), plain partial store.
__global__ __launch_bounds__(BLOCK, 2) void energy_partial_kernel(
    const float* __restrict__ mean, const float* __restrict__ variance,
    const float* __restrict__ noise, const float* __restrict__ target,
    float* __restrict__ partial) {
    const int tid  = threadIdx.x;
    const int wg   = (blockIdx.x & 7) * (GRIDN / 8) + (blockIdx.x >> 3);
    const int col0 = wg * (BLOCK * EPT) + tid * EPT;
    float e = energy_pair_packed(mean, variance, noise, target, col0);
    float bs = block_reduce(e, tid);
    if (tid == 0) partial[blockIdx.x] = bs;
}

// Stage 2: one block sums the partials, writes the scalar output.
__global__ __launch_bounds__(BLOCK) void reduce_partial_kernel(
    const float* __restrict__ partial, float* __restrict__ out) {
    float e = 0.0f;
    #pragma unroll
    for (int i = 0; i < GRIDN / BLOCK; ++i)
        e += partial[i * BLOCK + threadIdx.x];
    float bs = block_reduce(e, threadIdx.x);
    if (threadIdx.x == 0) out[0] = bs;   // overwrites poison
}

// Fallback (ws too small): single-kernel atomic path, same pipeline.
__global__ __launch_bounds__(BLOCK, 2) void energy_atomic_kernel(
    const float* __restrict__ mean, const float* __restrict__ variance,
    const float* __restrict__ noise, const float* __restrict__ target,
    float* __restrict__ out) {
    const int tid  = threadIdx.x;
    const int wg   = (blockIdx.x & 7) * (GRIDN / 8) + (blockIdx.x >> 3);
    const int col0 = wg * (BLOCK * EPT) + tid * EPT;
    float e = energy_pair_packed(mean, variance, noise, target, col0);
    float bs = block_reduce(e, tid);
    if (tid == 0) atomicAdd(out, bs);
}

extern "C" void kernel_launch(void* const* d_in, const int* in_sizes, int n_in,
                              void* d_out, int out_size, void* d_ws, size_t ws_size,
                              hipStream_t stream) {
    const float* mean     = (const float*)d_in[0];
    const float* variance = (const float*)d_in[1];
    const float* noise    = (const float*)d_in[2];
    const float* target   = (const float*)d_in[3];
    float* out = (float*)d_out;

    if (ws_size >= (size_t)GRIDN * sizeof(float)) {
        float* partial = (float*)d_ws;
        energy_partial_kernel<<<GRIDN, BLOCK, 0, stream>>>(mean, variance, noise,
                                                           target, partial);
        reduce_partial_kernel<<<1, BLOCK, 0, stream>>>(partial, out);
    } else {
        (void)hipMemsetAsync(out, 0, sizeof(float), stream);
        energy_atomic_kernel<<<GRIDN, BLOCK, 0, stream>>>(mean, variance, noise,
                                                          target, out);
    }
}

// Round 18
// 28.014 us; speedup vs baseline: 1.1128x; 1.0286x over previous
//
#include <hip/hip_runtime.h>
#include <float.h>

#define NS 50
#define NP 64              // padded to power of two for the sorting network
#define B_DIM 8192
#define D_DIM 64
#define BD (B_DIM * D_DIM)
#define BLOCK 256
#define EPT 2
#define GRIDN (BD / (BLOCK * EPT))   // 1024 blocks

typedef __fp16 f16x2 __attribute__((ext_vector_type(2)));

// Big LDS block (62.5 KB) -> 2 blocks/CU residency cap (R15: best). Only the
// first 4 floats are used (wave sums).
#define WSUM_FLOATS 16000

__device__ __forceinline__ float block_reduce(float e, int tid) {
    #pragma unroll
    for (int off = 32; off > 0; off >>= 1)
        e += __shfl_down(e, off, 64);
    __shared__ float wsum[WSUM_FLOATS];
    const int lane = tid & 63;
    const int wid  = tid >> 6;
    if (lane == 0) wsum[wid] = e;
    __syncthreads();
    float bs = 0.0f;
    if (tid == 0) {
        #pragma unroll
        for (int w = 0; w < BLOCK / 64; ++w) bs += wsum[w];
    }
    return bs;
}

__device__ __forceinline__ void cmpx(f16x2& a, f16x2& b) {
    f16x2 lo = __builtin_elementwise_min(a, b);
    f16x2 hi = __builtin_elementwise_max(a, b);
    a = lo; b = hi;
}

// Batcher odd-even mergesort, n=64: 543 comparators (vs bitonic's 672).
// All loop bounds/conditions compile-time -> fully unrolled, static indices.
__device__ __forceinline__ void sort_packed(f16x2* p) {
    #pragma unroll
    for (int q = 1; q < NP; q <<= 1) {
        #pragma unroll
        for (int k = q; k >= 1; k >>= 1) {
            #pragma unroll
            for (int j = k % q; j + k < NP; j += 2 * k) {
                #pragma unroll
                for (int i = 0; i < k; ++i) {
                    if (i + j + k < NP &&
                        (i + j) / (2 * q) == (i + j + k) / (2 * q)) {
                        cmpx(p[i + j], p[i + j + k]);
                    }
                }
            }
        }
    }
}

// Two elements per thread, ONE packed-f16 network sorting both lanes
// (packed pipeline verified R14/R15, absmax 0.0).
__device__ __forceinline__ float energy_pair_packed(
    const float* __restrict__ mean, const float* __restrict__ variance,
    const float* __restrict__ noise, const float* __restrict__ target,
    int col0) {

    // ---- Params first; materialize so the compiler's own waitcnt for them
    // lands BEFORE the counted asm-load block.
    const float2 mv = *(const float2*)(mean + col0);
    const float2 vv = *(const float2*)(variance + col0);
    const float2 tv = *(const float2*)(target + col0);
    float mA = mv.x, mB = mv.y;
    float tA = tv.x, tB = tv.y;
    float sdA = sqrtf(vv.x + 1e-6f);
    float sdB = sqrtf(vv.y + 1e-6f);
    asm volatile("" : "+v"(mA), "+v"(tA), "+v"(sdA), "+v"(mB), "+v"(tB), "+v"(sdB));

    // ---- 50 dwordx2 loads (adjacent columns), order pinned, all in flight.
    float2 f2[NS];
    const unsigned voff = (unsigned)col0 * 4u;
    #pragma unroll
    for (int k = 0; k < NS; ++k) {
        const unsigned ok = voff + (unsigned)k * (unsigned)(BD * 4);
        asm volatile("global_load_dwordx2 %0, %1, %2"
                     : "=v"(f2[k]) : "v"(ok), "s"(noise));
    }
    asm volatile("s_waitcnt vmcnt(0)" ::: "memory");
    __builtin_amdgcn_sched_barrier(0);

    // ---- Samples + first term in f32 (precision path), pack to f16x2.
    float fA0 = 0.0f, fA1 = 0.0f, fB0 = 0.0f, fB1 = 0.0f;
    f16x2 p[NP];
    #pragma unroll
    for (int k = 0; k < NS; ++k) {
        float sa = fmaf(f2[k].x, sdA, mA);
        float sb = fmaf(f2[k].y, sdB, mB);
        float dA = fabsf(sa - tA);
        float dB = fabsf(sb - tB);
        if (k & 1) { fA1 += dA; fB1 += dB; }
        else       { fA0 += dA; fB0 += dB; }
        p[k] = __builtin_amdgcn_cvt_pkrtz(sa, sb);   // v_cvt_pkrtz_f16_f32
    }
    const f16x2 pad = {(__fp16)65504.0f, (__fp16)65504.0f};
    #pragma unroll
    for (int k = NS; k < NP; ++k) p[k] = pad;

    // ---- Packed Batcher sort: one network sorts BOTH lanes via
    // v_pk_min_f16/v_pk_max_f16.
    sort_packed(p);

    // ---- Pair term via sort identity, accumulated in f32.
    float pA0 = 0.0f, pA1 = 0.0f;
    #pragma unroll
    for (int k = 0; k < NS; ++k) {
        const float c = (float)(2 * k - (NS - 1));
        float s = (float)p[k][0] + (float)p[k][1];
        if (k & 1) pA1 = fmaf(c, s, pA1);
        else       pA0 = fmaf(c, s, pA0);
    }

    float e = (fA0 + fA1 + fB0 + fB1) * (1.0f / NS)
            - (pA0 + pA1) * (1.0f / 2450.0f);
    return e * (1.0f / (float)BD);   // pre-scale for global mean
}

// Stage 1: XCD-swizzled (GRIDN % 8 == 0, bijective), plain partial store.
__global__ __launch_bounds__(BLOCK, 2) void energy_partial_kernel(
    const float* __restrict__ mean, const float* __restrict__ variance,
    const float* __restrict__ noise, const float* __restrict__ target,
    float* __restrict__ partial) {
    const int tid  = threadIdx.x;
    const int wg   = (blockIdx.x & 7) * (GRIDN / 8) + (blockIdx.x >> 3);
    const int col0 = wg * (BLOCK * EPT) + tid * EPT;
    float e = energy_pair_packed(mean, variance, noise, target, col0);
    float bs = block_reduce(e, tid);
    if (tid == 0) partial[blockIdx.x] = bs;
}

// Stage 2: one block sums the partials, writes the scalar output.
__global__ __launch_bounds__(BLOCK) void reduce_partial_kernel(
    const float* __restrict__ partial, float* __restrict__ out) {
    float e = 0.0f;
    #pragma unroll
    for (int i = 0; i < GRIDN / BLOCK; ++i)
        e += partial[i * BLOCK + threadIdx.x];
    // small shared block here (separate kernel, no throttle needed)
    #pragma unroll
    for (int off = 32; off > 0; off >>= 1)
        e += __shfl_down(e, off, 64);
    __shared__ float ws2[BLOCK / 64];
    const int lane = threadIdx.x & 63;
    const int wid  = threadIdx.x >> 6;
    if (lane == 0) ws2[wid] = e;
    __syncthreads();
    if (threadIdx.x == 0) {
        float bs = 0.0f;
        #pragma unroll
        for (int w = 0; w < BLOCK / 64; ++w) bs += ws2[w];
        out[0] = bs;   // overwrites poison
    }
}

// Fallback (ws too small): single-kernel atomic path, same pipeline.
__global__ __launch_bounds__(BLOCK, 2) void energy_atomic_kernel(
    const float* __restrict__ mean, const float* __restrict__ variance,
    const float* __restrict__ noise, const float* __restrict__ target,
    float* __restrict__ out) {
    const int tid  = threadIdx.x;
    const int wg   = (blockIdx.x & 7) * (GRIDN / 8) + (blockIdx.x >> 3);
    const int col0 = wg * (BLOCK * EPT) + tid * EPT;
    float e = energy_pair_packed(mean, variance, noise, target, col0);
    float bs = block_reduce(e, tid);
    if (tid == 0) atomicAdd(out, bs);
}

extern "C" void kernel_launch(void* const* d_in, const int* in_sizes, int n_in,
                              void* d_out, int out_size, void* d_ws, size_t ws_size,
                              hipStream_t stream) {
    const float* mean     = (const float*)d_in[0];
    const float* variance = (const float*)d_in[1];
    const float* noise    = (const float*)d_in[2];
    const float* target   = (const float*)d_in[3];
    float* out = (float*)d_out;

    if (ws_size >= (size_t)GRIDN * sizeof(float)) {
        float* partial = (float*)d_ws;
        energy_partial_kernel<<<GRIDN, BLOCK, 0, stream>>>(mean, variance, noise,
                                                           target, partial);
        reduce_partial_kernel<<<1, BLOCK, 0, stream>>>(partial, out);
    } else {
        (void)hipMemsetAsync(out, 0, sizeof(float), stream);
        energy_atomic_kernel<<<GRIDN, BLOCK, 0, stream>>>(mean, variance, noise,
                                                          target, out);
    }
}

// Round 19
// 27.605 us; speedup vs baseline: 1.1293x; 1.0148x over previous
//
#include <hip/hip_runtime.h>
#include <float.h>

#define NS 50
#define NP 64              // padded to power of two for bitonic network
#define B_DIM 8192
#define D_DIM 64
#define BD (B_DIM * D_DIM)
#define BLOCK 256
#define EPT 2
#define GRIDN (BD / (BLOCK * EPT))   // 1024 blocks

typedef __fp16 f16x2 __attribute__((ext_vector_type(2)));

// Big LDS block (~62.5 KB) -> 2 blocks/CU residency cap (R15 best config).
// Only the first 4 floats are used (wave sums).
#define WSUM_FLOATS 16000

__device__ __forceinline__ float block_reduce(float e, int tid) {
    #pragma unroll
    for (int off = 32; off > 0; off >>= 1)
        e += __shfl_down(e, off, 64);
    __shared__ float wsum[WSUM_FLOATS];
    const int lane = tid & 63;
    const int wid  = tid >> 6;
    if (lane == 0) wsum[wid] = e;
    __syncthreads();
    float bs = 0.0f;
    if (tid == 0) {
        #pragma unroll
        for (int w = 0; w < BLOCK / 64; ++w) bs += wsum[w];
    }
    return bs;
}

// Two elements per thread, ONE packed-f16 bitonic network sorting both
// (verified R14/R15, absmax 0.0).
__device__ __forceinline__ float energy_pair_packed(
    const float* __restrict__ mean, const float* __restrict__ variance,
    const float* __restrict__ noise, const float* __restrict__ target,
    int col0) {

    // ---- Params first; force materialization so the compiler's waitcnt for
    // them precedes the counted asm-load block.
    const float2 mv = *(const float2*)(mean + col0);
    const float2 vv = *(const float2*)(variance + col0);
    const float2 tv = *(const float2*)(target + col0);
    float mA = mv.x, mB = mv.y;
    float tA = tv.x, tB = tv.y;
    float sdA = sqrtf(vv.x + 1e-6f);
    float sdB = sqrtf(vv.y + 1e-6f);
    asm volatile("" : "+v"(mA), "+v"(tA), "+v"(sdA), "+v"(mB), "+v"(tB), "+v"(sdB));

    // ---- 50 dwordx2 loads (adjacent columns), order pinned, all in flight.
    float2 f2[NS];
    const unsigned voff = (unsigned)col0 * 4u;
    #pragma unroll
    for (int k = 0; k < NS; ++k) {
        const unsigned ok = voff + (unsigned)k * (unsigned)(BD * 4);
        asm volatile("global_load_dwordx2 %0, %1, %2"
                     : "=v"(f2[k]) : "v"(ok), "s"(noise));
    }
    asm volatile("s_waitcnt vmcnt(0)" ::: "memory");
    __builtin_amdgcn_sched_barrier(0);

    // ---- Samples + first term in f32 (precision path), pack to f16x2.
    float fA0 = 0.0f, fA1 = 0.0f, fB0 = 0.0f, fB1 = 0.0f;
    f16x2 p[NP];
    #pragma unroll
    for (int k = 0; k < NS; ++k) {
        float sa = fmaf(f2[k].x, sdA, mA);
        float sb = fmaf(f2[k].y, sdB, mB);
        float dA = fabsf(sa - tA);
        float dB = fabsf(sb - tB);
        if (k & 1) { fA1 += dA; fB1 += dB; }
        else       { fA0 += dA; fB0 += dB; }
        p[k] = __builtin_amdgcn_cvt_pkrtz(sa, sb);   // v_cvt_pkrtz_f16_f32
    }
    const f16x2 pad = {(__fp16)65504.0f, (__fp16)65504.0f};
    #pragma unroll
    for (int k = NS; k < NP; ++k) p[k] = pad;

    // ---- Packed bitonic sort: one network sorts BOTH lanes via
    // v_pk_min_f16/v_pk_max_f16. Compile-time dirs -> pure min/max.
    #pragma unroll
    for (int k = 2; k <= NP; k <<= 1) {
        #pragma unroll
        for (int j = k >> 1; j > 0; j >>= 1) {
            #pragma unroll
            for (int i = 0; i < NP; ++i) {
                const int l = i ^ j;
                if (l > i) {
                    const bool up = ((i & k) == 0);
                    f16x2 x = p[i], y = p[l];
                    f16x2 lo = __builtin_elementwise_min(x, y);
                    f16x2 hi = __builtin_elementwise_max(x, y);
                    p[i] = up ? lo : hi;   // compile-time select
                    p[l] = up ? hi : lo;
                }
            }
        }
    }

    // ---- Pair term via sort identity, accumulated in f32.
    float pA0 = 0.0f, pA1 = 0.0f, pB0 = 0.0f, pB1 = 0.0f;
    #pragma unroll
    for (int k = 0; k < NS; ++k) {
        const float c = (float)(2 * k - (NS - 1));
        float sa = (float)p[k][0];
        float sb = (float)p[k][1];
        if (k & 1) { pA1 = fmaf(c, sa, pA1); pB1 = fmaf(c, sb, pB1); }
        else       { pA0 = fmaf(c, sa, pA0); pB0 = fmaf(c, sb, pB0); }
    }

    float e = (fA0 + fA1 + fB0 + fB1) * (1.0f / NS)
            - (pA0 + pA1 + pB0 + pB1) * (1.0f / 2450.0f);
    return e * (1.0f / (float)BD);   // pre-scale for global mean
}

// Stage 1: XCD-swizzled (GRIDN % 8 == 0, bijective), plain partial store.
__global__ __launch_bounds__(BLOCK, 2) void energy_partial_kernel(
    const float* __restrict__ mean, const float* __restrict__ variance,
    const float* __restrict__ noise, const float* __restrict__ target,
    float* __restrict__ partial) {
    const int tid  = threadIdx.x;
    const int wg   = (blockIdx.x & 7) * (GRIDN / 8) + (blockIdx.x >> 3);
    const int col0 = wg * (BLOCK * EPT) + tid * EPT;
    float e = energy_pair_packed(mean, variance, noise, target, col0);
    float bs = block_reduce(e, tid);
    if (tid == 0) partial[blockIdx.x] = bs;
}

// Stage 2: one block sums the partials, writes the scalar output.
__global__ __launch_bounds__(BLOCK) void reduce_partial_kernel(
    const float* __restrict__ partial, float* __restrict__ out) {
    float e = 0.0f;
    #pragma unroll
    for (int i = 0; i < GRIDN / BLOCK; ++i)
        e += partial[i * BLOCK + threadIdx.x];
    #pragma unroll
    for (int off = 32; off > 0; off >>= 1)
        e += __shfl_down(e, off, 64);
    __shared__ float ws2[BLOCK / 64];
    const int lane = threadIdx.x & 63;
    const int wid  = threadIdx.x >> 6;
    if (lane == 0) ws2[wid] = e;
    __syncthreads();
    if (threadIdx.x == 0) {
        float bs = 0.0f;
        #pragma unroll
        for (int w = 0; w < BLOCK / 64; ++w) bs += ws2[w];
        out[0] = bs;   // overwrites poison
    }
}

// Fallback (ws too small): single-kernel atomic path, same pipeline.
__global__ __launch_bounds__(BLOCK, 2) void energy_atomic_kernel(
    const float* __restrict__ mean, const float* __restrict__ variance,
    const float* __restrict__ noise, const float* __restrict__ target,
    float* __restrict__ out) {
    const int tid  = threadIdx.x;
    const int wg   = (blockIdx.x & 7) * (GRIDN / 8) + (blockIdx.x >> 3);
    const int col0 = wg * (BLOCK * EPT) + tid * EPT;
    float e = energy_pair_packed(mean, variance, noise, target, col0);
    float bs = block_reduce(e, tid);
    if (tid == 0) atomicAdd(out, bs);
}

extern "C" void kernel_launch(void* const* d_in, const int* in_sizes, int n_in,
                              void* d_out, int out_size, void* d_ws, size_t ws_size,
                              hipStream_t stream) {
    const float* mean     = (const float*)d_in[0];
    const float* variance = (const float*)d_in[1];
    const float* noise    = (const float*)d_in[2];
    const float* target   = (const float*)d_in[3];
    float* out = (float*)d_out;

    if (ws_size >= (size_t)GRIDN * sizeof(float)) {
        float* partial = (float*)d_ws;
        energy_partial_kernel<<<GRIDN, BLOCK, 0, stream>>>(mean, variance, noise,
                                                           target, partial);
        reduce_partial_kernel<<<1, BLOCK, 0, stream>>>(partial, out);
    } else {
        (void)hipMemsetAsync(out, 0, sizeof(float), stream);
        energy_atomic_kernel<<<GRIDN, BLOCK, 0, stream>>>(mean, variance, noise,
                                                          target, out);
    }
}